// Round 1
// baseline (2342.101 us; speedup 1.0000x reference)
//
#include <hip/hip_runtime.h>
#include <hip/hip_bf16.h>
#include <stdint.h>

// Problem shape (fixed by reference): M = B*S = 8192, K = 4096, N = 16384
#define M_TOT 8192
#define K_TOT 4096
#define N_TOT 16384

#define BM 128
#define BN 128
#define BK 64

typedef __attribute__((ext_vector_type(8))) short shortx8;   // 8 bf16 (4 VGPRs)
typedef __attribute__((ext_vector_type(4))) float floatx4;   // MFMA C/D

struct alignas(8) us4 { unsigned short x, y, z, w; };

// float -> bf16 RNE (manual, avoids header API variance; exact for small ints)
__device__ inline unsigned short f2bf(float f) {
    unsigned int u = __float_as_uint(f);
    unsigned int r = (u + 0x7fffu + ((u >> 16) & 1u)) >> 16;
    return (unsigned short)r;
}

// ---------------- conversion pre-passes (memory-bound) ----------------

__global__ __launch_bounds__(256) void cvt_a_kernel(const float* __restrict__ in,
                                                    unsigned short* __restrict__ out) {
    size_t i = ((size_t)blockIdx.x * 256 + threadIdx.x) * 4;
    float4 v = *(const float4*)(in + i);
    us4 o;
    o.x = f2bf(v.x); o.y = f2bf(v.y); o.z = f2bf(v.z); o.w = f2bf(v.w);
    *(us4*)(out + i) = o;
}

__global__ __launch_bounds__(256) void cvt_w_kernel(const int* __restrict__ in,
                                                    unsigned short* __restrict__ out) {
    size_t i = ((size_t)blockIdx.x * 256 + threadIdx.x) * 4;
    int4 v = *(const int4*)(in + i);
    us4 o;  // int8-valued -> exact in bf16
    o.x = f2bf((float)v.x); o.y = f2bf((float)v.y);
    o.z = f2bf((float)v.z); o.w = f2bf((float)v.w);
    *(us4*)(out + i) = o;
}

// ---------------- m97-style bf16 MFMA GEMM (B^T input) ----------------

__device__ inline void gload_lds16(const void* g, void* l) {
    __builtin_amdgcn_global_load_lds((const __attribute__((address_space(1))) void*)g,
                                     (__attribute__((address_space(3))) void*)l,
                                     16, 0, 0);
}

__global__ __launch_bounds__(256) void gemm_bf16_kernel(
        const unsigned short* __restrict__ A,   // [M][K] bf16 bits
        const unsigned short* __restrict__ W,   // [N][K] bf16 bits (B^T layout)
        const float* __restrict__ scale,        // [N]
        const float* __restrict__ bias,         // [N]
        float* __restrict__ out)                // [M][N]
{
    // Unpadded LDS layout: required by global_load_lds (wave-uniform base + lane*16)
    __shared__ alignas(16) unsigned short sA[BM * BK];
    __shared__ alignas(16) unsigned short sW[BN * BK];

    const int tid  = threadIdx.x;
    const int lane = tid & 63;
    const int wave = tid >> 6;
    const int l15  = lane & 15;
    const int quad = lane >> 4;

    const int mBlk = blockIdx.y * BM;
    const int nBlk = blockIdx.x * BN;

    const int waveM = (wave >> 1) * 64;  // 2x2 wave grid, 64x64 per wave
    const int waveN = (wave & 1) * 64;

    floatx4 acc[4][4];
#pragma unroll
    for (int i = 0; i < 4; ++i)
#pragma unroll
        for (int j = 0; j < 4; ++j)
            acc[i][j] = (floatx4){0.f, 0.f, 0.f, 0.f};

    for (int kt = 0; kt < K_TOT; kt += BK) {
        __syncthreads();  // previous tile fully consumed before overwrite
#pragma unroll
        for (int it = 0; it < 4; ++it) {
            // chunk c covers 16B = 8 bf16; row = c>>3 (BK=64 -> 8 chunks/row)
            int c   = it * 256 + tid;
            int row = c >> 3;
            int kin = (c & 7) * 8;
            gload_lds16(A + (size_t)(mBlk + row) * K_TOT + kt + kin, (char*)sA + c * 16);
            gload_lds16(W + (size_t)(nBlk + row) * K_TOT + kt + kin, (char*)sW + c * 16);
        }
        __syncthreads();  // compiler drains vmcnt before s_barrier

#pragma unroll
        for (int kk = 0; kk < BK; kk += 32) {
            shortx8 af[4], bfr[4];
#pragma unroll
            for (int i = 0; i < 4; ++i)
                af[i] = *(const shortx8*)(sA + (waveM + i * 16 + l15) * BK + kk + quad * 8);
#pragma unroll
            for (int j = 0; j < 4; ++j)
                bfr[j] = *(const shortx8*)(sW + (waveN + j * 16 + l15) * BK + kk + quad * 8);
#pragma unroll
            for (int i = 0; i < 4; ++i)
#pragma unroll
                for (int j = 0; j < 4; ++j)
                    acc[i][j] = __builtin_amdgcn_mfma_f32_16x16x32_bf16(
                        af[i], bfr[j], acc[i][j], 0, 0, 0);
        }
    }

    // Epilogue: C/D layout col = lane&15, row = quad*4 + reg (measured m89/m91)
#pragma unroll
    for (int j = 0; j < 4; ++j) {
        int col = nBlk + waveN + j * 16 + l15;
        float sc = scale[col];
        float bi = bias[col];
#pragma unroll
        for (int i = 0; i < 4; ++i) {
            int row0 = mBlk + waveM + i * 16 + quad * 4;
#pragma unroll
            for (int r = 0; r < 4; ++r)
                out[(size_t)(row0 + r) * N_TOT + col] = acc[i][j][r] * sc + bi;
        }
    }
}

// ---------------- launch ----------------

extern "C" void kernel_launch(void* const* d_in, const int* in_sizes, int n_in,
                              void* d_out, int out_size, void* d_ws, size_t ws_size,
                              hipStream_t stream) {
    const float* inp    = (const float*)d_in[0];   // [B,S,K] fp32
    const int*   weight = (const int*)d_in[1];     // [N,K] int32 (int8-valued)
    const float* wscale = (const float*)d_in[2];   // [N]
    const float* bias   = (const float*)d_in[3];   // [N]
    float* out = (float*)d_out;

    // Workspace: A_bf16 (64 MB) then W_bf16 (128 MB)
    unsigned short* Abf = (unsigned short*)d_ws;
    unsigned short* Wbf = Abf + (size_t)M_TOT * K_TOT;

    {
        size_t n4 = (size_t)M_TOT * K_TOT / 4;  // 8,388,608
        cvt_a_kernel<<<(unsigned)(n4 / 256), 256, 0, stream>>>(inp, Abf);
    }
    {
        size_t n4 = (size_t)N_TOT * K_TOT / 4;  // 16,777,216
        cvt_w_kernel<<<(unsigned)(n4 / 256), 256, 0, stream>>>(weight, Wbf);
    }

    dim3 grid(N_TOT / BN, M_TOT / BM);  // (128, 64) = 8192 blocks
    gemm_bf16_kernel<<<grid, 256, 0, stream>>>(Abf, Wbf, wscale, bias, out);
}